// Round 1
// baseline (1221.879 us; speedup 1.0000x reference)
//
#include <hip/hip_runtime.h>
#include <cstdint>
#include <cstddef>

// ---------------------------------------------------------------------------
// AffineModulatedLatentODEFunc: fp32 baseline
//   kernel 1: MLP  t,mu -> sinenc -> elu(W1) -> elu(W2) -> Wg -> gb (B,256) in ws
//   kernel 2: conv pipeline on 4x4 latent, gated by gb
// ---------------------------------------------------------------------------

#define NB 32768  // batch

__device__ __forceinline__ float fast_tanh(float x) {
  float ax = fabsf(x);
  float e = __expf(-2.0f * ax);           // in (0,1], no overflow
  float r = __fdividef(1.0f - e, 1.0f + e);
  return copysignf(r, x);
}

__device__ __forceinline__ float elu_f(float v) {
  return v > 0.0f ? v : (__expf(v) - 1.0f);
}

// 3x3 "same" conv on a 4x4 tile, fully unrolled -> 100 FMAs
__device__ __forceinline__ void conv_acc(float acc[16], const float r[16], const float w[9]) {
#pragma unroll
  for (int y = 0; y < 4; ++y)
#pragma unroll
    for (int x = 0; x < 4; ++x)
#pragma unroll
      for (int ky = 0; ky < 3; ++ky) {
        int iy = y + ky - 1;
        if (iy < 0 || iy >= 4) continue;
#pragma unroll
        for (int kx = 0; kx < 3; ++kx) {
          int ix = x + kx - 1;
          if (ix < 0 || ix >= 4) continue;
          acc[y * 4 + x] += w[ky * 3 + kx] * r[iy * 4 + ix];
        }
      }
}

// ---------------------------------------------------------------------------
// MLP kernel: 128 threads, 16 samples per block
// ---------------------------------------------------------------------------
__global__ __launch_bounds__(128) void mlp_kernel(
    const float* __restrict__ tt, const float* __restrict__ mu,
    const float* __restrict__ W1, const float* __restrict__ b1,
    const float* __restrict__ W2, const float* __restrict__ b2,
    const float* __restrict__ Wg, const float* __restrict__ bg,
    float* __restrict__ gbo) {
  const int tid = threadIdx.x;
  const int s0 = blockIdx.x * 16;

  __shared__ float xs[16][32];
  __shared__ float hs[16][128];
  __shared__ float xis[16][128];

  const float TM = 31.41592653589793f;
  const float F1v = 1.0f / TM;
  const float F2v = 1.0f / (TM * TM);
  const float F3v = 1.0f / (TM * TM * TM);

  // phase 0: embeddings x = [sinenc(t) | sinenc(mu)]  (16 samples x 32 dims)
  for (int i = tid; i < 16 * 32; i += 128) {
    int s = i >> 5, k = i & 31;
    float base;
    int j;
    bool is_sin;
    if (k < 8) {
      base = tt[s0 + s];
      j = k & 3;
      is_sin = (k < 4);
    } else {
      int km = k - 8;
      int d = km >> 3;
      int kk = km & 7;
      base = mu[(size_t)(s0 + s) * 3 + d];
      j = kk & 3;
      is_sin = (kk < 4);
    }
    float fr = (j == 0) ? 1.0f : (j == 1) ? F1v : (j == 2) ? F2v : F3v;
    float a = base * fr;
    xs[s][k] = is_sin ? sinf(a) : cosf(a);
  }
  __syncthreads();

  // phase 1: h = elu(x @ W1 + b1)   (thread = output unit)
  {
    float acc[16];
#pragma unroll
    for (int s = 0; s < 16; ++s) acc[s] = 0.0f;
    for (int k = 0; k < 32; ++k) {
      float w = W1[k * 128 + tid];
#pragma unroll
      for (int s = 0; s < 16; ++s) acc[s] += xs[s][k] * w;
    }
    float bb = b1[tid];
#pragma unroll
    for (int s = 0; s < 16; ++s) hs[s][tid] = elu_f(acc[s] + bb);
  }
  __syncthreads();

  // phase 2: xi = elu(h @ W2 + b2)
  {
    float acc[16];
#pragma unroll
    for (int s = 0; s < 16; ++s) acc[s] = 0.0f;
    for (int k = 0; k < 128; ++k) {
      float w = W2[k * 128 + tid];
#pragma unroll
      for (int s = 0; s < 16; ++s) acc[s] += hs[s][k] * w;
    }
    float bb = b2[tid];
#pragma unroll
    for (int s = 0; s < 16; ++s) xis[s][tid] = elu_f(acc[s] + bb);
  }
  __syncthreads();

  // phase 3: gb = xi @ Wg + bg  (each thread: columns tid and tid+128)
  {
    float a0[16], a1[16];
#pragma unroll
    for (int s = 0; s < 16; ++s) { a0[s] = 0.0f; a1[s] = 0.0f; }
    for (int k = 0; k < 128; ++k) {
      float w0 = Wg[k * 256 + tid];
      float w1 = Wg[k * 256 + 128 + tid];
#pragma unroll
      for (int s = 0; s < 16; ++s) {
        float v = xis[s][k];
        a0[s] += v * w0;
        a1[s] += v * w1;
      }
    }
    float bg0 = bg[tid], bg1 = bg[128 + tid];
#pragma unroll
    for (int s = 0; s < 16; ++s) {
      size_t o = (size_t)(s0 + s) * 256;
      gbo[o + tid] = a0[s] + bg0;
      gbo[o + 128 + tid] = a1[s] + bg1;
    }
  }
}

// ---------------------------------------------------------------------------
// conv mid-layer: 64 in-ch -> 64 out-ch, 3x3 pad-1 on 4x4, gated tanh
// lane = out channel; 2 samples per wave; weights double-buffered in regs
// ---------------------------------------------------------------------------
__device__ __forceinline__ void mid_layer(
    const float (*src)[16][65], float (*dst)[16][65],
    const float* __restrict__ wlayer, float bias,
    const float g[2], const float bbv[2], int oc) {
  float acc[2][16];
#pragma unroll
  for (int s = 0; s < 2; ++s)
#pragma unroll
    for (int p = 0; p < 16; ++p) acc[s][p] = 0.0f;

  const float* wbase = wlayer + (size_t)oc * 576;  // 64 ic * 9 taps
  float wc[9], wn[9];
#pragma unroll
  for (int tp = 0; tp < 9; ++tp) wc[tp] = wbase[tp];

  for (int ic = 0; ic < 64; ++ic) {
    // prefetch next ic's taps (dummy re-load of ic 0 on last iter)
    const float* wnp = wbase + ((ic < 63) ? (ic + 1) * 9 : 0);
#pragma unroll
    for (int tp = 0; tp < 9; ++tp) wn[tp] = wnp[tp];

#pragma unroll
    for (int s = 0; s < 2; ++s) {
      float r[16];
#pragma unroll
      for (int q = 0; q < 16; ++q) r[q] = src[s][q][ic];  // wave-broadcast
      conv_acc(acc[s], r, wc);
    }
#pragma unroll
    for (int tp = 0; tp < 9; ++tp) wc[tp] = wn[tp];
  }

#pragma unroll
  for (int s = 0; s < 2; ++s)
#pragma unroll
    for (int p = 0; p < 16; ++p)
      dst[s][p][oc] = fast_tanh(g[s] * (acc[s][p] + bias) + bbv[s]);
}

__global__ __launch_bounds__(64) void conv_kernel(
    const float* __restrict__ z, const float* __restrict__ gb,
    const float* __restrict__ cin_w, const float* __restrict__ cin_b,
    const float* __restrict__ c1_w, const float* __restrict__ c1_b,
    const float* __restrict__ c2_w, const float* __restrict__ c2_b,
    const float* __restrict__ cout_w, const float* __restrict__ cout_b,
    float* __restrict__ out) {
  const int lane = threadIdx.x;   // 0..63
  const int sb = blockIdx.x * 2;  // 2 samples per block (1 wave)

  __shared__ float hA[2][16][65];
  __shared__ float hB[2][16][65];
  __shared__ float zb[2][16];

  if (lane < 32) zb[lane >> 4][lane & 15] = z[(size_t)sb * 16 + lane];
  __syncthreads();

  const int oc = lane;
  float g1r[2], g2r[2], bb1r[2], bb2r[2];
#pragma unroll
  for (int s = 0; s < 2; ++s) {
    const float* gp = gb + (size_t)(sb + s) * 256;
    g1r[s] = gp[oc];
    g2r[s] = gp[64 + oc];
    bb1r[s] = gp[128 + oc];
    bb2r[s] = gp[192 + oc];
  }

  // ---- cin: z (1ch) -> hA (64ch), tanh ----
  {
    float w[9];
#pragma unroll
    for (int tp = 0; tp < 9; ++tp) w[tp] = cin_w[oc * 9 + tp];
    float cb = cin_b[oc];
#pragma unroll
    for (int s = 0; s < 2; ++s) {
      float r[16];
#pragma unroll
      for (int q = 0; q < 16; ++q) r[q] = zb[s][q];
      float acc[16];
#pragma unroll
      for (int p = 0; p < 16; ++p) acc[p] = 0.0f;
      conv_acc(acc, r, w);
#pragma unroll
      for (int p = 0; p < 16; ++p) hA[s][p][oc] = fast_tanh(acc[p] + cb);
    }
  }
  __syncthreads();

  // ---- c1: hA -> hB,  tanh(g1*(conv+b) + bb1) ----
  mid_layer(hA, hB, c1_w, c1_b[oc], g1r, bb1r, oc);
  __syncthreads();

  // ---- c2: hB -> hA,  tanh(g2*(conv+b) + bb2) ----
  mid_layer(hB, hA, c2_w, c2_b[oc], g2r, bb2r, oc);
  __syncthreads();

  // ---- cout: hA (64ch) -> out (1ch); lane = (s, half, pixel) ----
  {
    const int s = lane >> 5;
    const int r = lane & 31;
    const int p = r & 15;
    const int hf = r >> 4;
    const int y = p >> 2, x = p & 3;

    float m[9];
    int off[9];
#pragma unroll
    for (int ky = 0; ky < 3; ++ky)
#pragma unroll
      for (int kx = 0; kx < 3; ++kx) {
        int iy = y + ky - 1, ix = x + kx - 1;
        bool v = (iy >= 0 && iy < 4 && ix >= 0 && ix < 4);
        m[ky * 3 + kx] = v ? 1.0f : 0.0f;
        off[ky * 3 + kx] = (v ? iy : 0) * 4 + (v ? ix : 0);
      }

    float acc = 0.0f;
    const int ic0 = hf * 32;
    for (int ic = ic0; ic < ic0 + 32; ++ic) {
#pragma unroll
      for (int tp = 0; tp < 9; ++tp)
        acc += m[tp] * cout_w[ic * 9 + tp] * hA[s][off[tp]][ic];
    }
    acc += __shfl_xor(acc, 16);
    if (hf == 0) out[(size_t)(sb + s) * 16 + p] = acc + cout_b[0];
  }
}

// ---------------------------------------------------------------------------
extern "C" void kernel_launch(void* const* d_in, const int* in_sizes, int n_in,
                              void* d_out, int out_size, void* d_ws, size_t ws_size,
                              hipStream_t stream) {
  const float* tt     = (const float*)d_in[0];
  const float* z      = (const float*)d_in[1];
  const float* mu     = (const float*)d_in[2];
  const float* W1     = (const float*)d_in[3];
  const float* b1     = (const float*)d_in[4];
  const float* W2     = (const float*)d_in[5];
  const float* b2     = (const float*)d_in[6];
  const float* Wg     = (const float*)d_in[7];
  const float* bg     = (const float*)d_in[8];
  const float* cin_w  = (const float*)d_in[9];
  const float* cin_b  = (const float*)d_in[10];
  const float* c1_w   = (const float*)d_in[11];
  const float* c1_b   = (const float*)d_in[12];
  const float* c2_w   = (const float*)d_in[13];
  const float* c2_b   = (const float*)d_in[14];
  const float* cout_w = (const float*)d_in[15];
  const float* cout_b = (const float*)d_in[16];

  float* out = (float*)d_out;
  float* gbo = (float*)d_ws;  // (B, 256) gate buffer, 32 MB

  mlp_kernel<<<NB / 16, 128, 0, stream>>>(tt, mu, W1, b1, W2, b2, Wg, bg, gbo);
  conv_kernel<<<NB / 2, 64, 0, stream>>>(z, gbo, cin_w, cin_b, c1_w, c1_b,
                                         c2_w, c2_b, cout_w, cout_b, out);
}

// Round 2
// 359.198 us; speedup vs baseline: 3.4017x; 3.4017x over previous
//
#include <hip/hip_runtime.h>
#include <cstdint>
#include <cstddef>

// ---------------------------------------------------------------------------
// AffineModulatedLatentODEFunc
//   kernel 1: MLP (fp32 VALU)  t,mu -> gb (B,256) in ws
//   kernel 2: conv pipeline, mid layers via f16 MFMA 16x16x32
// ---------------------------------------------------------------------------

#define NB 32768

typedef _Float16 half8  __attribute__((ext_vector_type(8)));
typedef _Float16 half4_t __attribute__((ext_vector_type(4)));
typedef _Float16 half2_t __attribute__((ext_vector_type(2)));
typedef float    f32x4  __attribute__((ext_vector_type(4)));

__device__ __forceinline__ float fast_tanh(float x) {
  float ax = fabsf(x);
  float e = __expf(-2.0f * ax);
  float r = __fdividef(1.0f - e, 1.0f + e);
  return copysignf(r, x);
}

__device__ __forceinline__ float elu_f(float v) {
  return v > 0.0f ? v : (__expf(v) - 1.0f);
}

// 3x3 "same" conv on a 4x4 tile, fully unrolled -> 100 FMAs
__device__ __forceinline__ void conv_acc(float acc[16], const float r[16], const float w[9]) {
#pragma unroll
  for (int y = 0; y < 4; ++y)
#pragma unroll
    for (int x = 0; x < 4; ++x)
#pragma unroll
      for (int ky = 0; ky < 3; ++ky) {
        int iy = y + ky - 1;
        if (iy < 0 || iy >= 4) continue;
#pragma unroll
        for (int kx = 0; kx < 3; ++kx) {
          int ix = x + kx - 1;
          if (ix < 0 || ix >= 4) continue;
          acc[y * 4 + x] += w[ky * 3 + kx] * r[iy * 4 + ix];
        }
      }
}

// ---------------------------------------------------------------------------
// MLP kernel (unchanged from round 1 — passed, ~2% of total time)
// ---------------------------------------------------------------------------
__global__ __launch_bounds__(128) void mlp_kernel(
    const float* __restrict__ tt, const float* __restrict__ mu,
    const float* __restrict__ W1, const float* __restrict__ b1,
    const float* __restrict__ W2, const float* __restrict__ b2,
    const float* __restrict__ Wg, const float* __restrict__ bg,
    float* __restrict__ gbo) {
  const int tid = threadIdx.x;
  const int s0 = blockIdx.x * 16;

  __shared__ float xs[16][32];
  __shared__ float hs[16][128];
  __shared__ float xis[16][128];

  const float TM = 31.41592653589793f;
  const float F1v = 1.0f / TM;
  const float F2v = 1.0f / (TM * TM);
  const float F3v = 1.0f / (TM * TM * TM);

  for (int i = tid; i < 16 * 32; i += 128) {
    int s = i >> 5, k = i & 31;
    float base;
    int j;
    bool is_sin;
    if (k < 8) {
      base = tt[s0 + s];
      j = k & 3;
      is_sin = (k < 4);
    } else {
      int km = k - 8;
      int d = km >> 3;
      int kk = km & 7;
      base = mu[(size_t)(s0 + s) * 3 + d];
      j = kk & 3;
      is_sin = (kk < 4);
    }
    float fr = (j == 0) ? 1.0f : (j == 1) ? F1v : (j == 2) ? F2v : F3v;
    float a = base * fr;
    xs[s][k] = is_sin ? sinf(a) : cosf(a);
  }
  __syncthreads();

  {
    float acc[16];
#pragma unroll
    for (int s = 0; s < 16; ++s) acc[s] = 0.0f;
    for (int k = 0; k < 32; ++k) {
      float w = W1[k * 128 + tid];
#pragma unroll
      for (int s = 0; s < 16; ++s) acc[s] += xs[s][k] * w;
    }
    float bb = b1[tid];
#pragma unroll
    for (int s = 0; s < 16; ++s) hs[s][tid] = elu_f(acc[s] + bb);
  }
  __syncthreads();

  {
    float acc[16];
#pragma unroll
    for (int s = 0; s < 16; ++s) acc[s] = 0.0f;
    for (int k = 0; k < 128; ++k) {
      float w = W2[k * 128 + tid];
#pragma unroll
      for (int s = 0; s < 16; ++s) acc[s] += hs[s][k] * w;
    }
    float bb = b2[tid];
#pragma unroll
    for (int s = 0; s < 16; ++s) xis[s][tid] = elu_f(acc[s] + bb);
  }
  __syncthreads();

  {
    float a0[16], a1[16];
#pragma unroll
    for (int s = 0; s < 16; ++s) { a0[s] = 0.0f; a1[s] = 0.0f; }
    for (int k = 0; k < 128; ++k) {
      float w0 = Wg[k * 256 + tid];
      float w1 = Wg[k * 256 + 128 + tid];
#pragma unroll
      for (int s = 0; s < 16; ++s) {
        float v = xis[s][k];
        a0[s] += v * w0;
        a1[s] += v * w1;
      }
    }
    float bg0 = bg[tid], bg1 = bg[128 + tid];
#pragma unroll
    for (int s = 0; s < 16; ++s) {
      size_t o = (size_t)(s0 + s) * 256;
      gbo[o + tid] = a0[s] + bg0;
      gbo[o + 128 + tid] = a1[s] + bg1;
    }
  }
}

// ---------------------------------------------------------------------------
// conv kernel: f16 MFMA for c1/c2
//   block = 256 thr (4 waves); wave = 16-oc M-tile; 4 samples in flight (N-tiles)
//   h stored zero-padded [6][6][72 f16] per sample in LDS; tap = pure offset
// ---------------------------------------------------------------------------
#define ROWE 72            // f16 elems per padded position (64 used, 16B-aligned stride)
#define SAMP (36 * ROWE)   // 2592 f16 per sample buffer
#define GS 4               // samples per group (MFMA N-tiles in flight)
#define GRPS 16            // groups per block -> 64 samples/block -> 512 blocks

__global__ __launch_bounds__(256, 2) void conv_kernel(
    const float* __restrict__ z, const float* __restrict__ gb,
    const float* __restrict__ cin_w, const float* __restrict__ cin_b,
    const float* __restrict__ c1_w, const float* __restrict__ c1_b,
    const float* __restrict__ c2_w, const float* __restrict__ c2_b,
    const float* __restrict__ cout_w, const float* __restrict__ cout_b,
    float* __restrict__ out) {
  const int tid = threadIdx.x;
  const int lane = tid & 63;
  const int wv = tid >> 6;          // wave id 0..3 = oc tile
  const int s0 = blockIdx.x * (GRPS * GS);

  __shared__ __align__(16) _Float16 hp[2 * GS * SAMP];  // [buf][sample][pos][ic]
  __shared__ __align__(16) _Float16 cwl[9 * 64];        // cout_w as [tap][ic] f16

  // zero-init hp (borders must be 0; interiors overwritten each group)
  for (int i = tid; i < (2 * GS * SAMP) / 2; i += 256) ((uint32_t*)hp)[i] = 0u;
  for (int i = tid; i < 576; i += 256) {
    int ic = i / 9, tap = i % 9;
    cwl[tap * 64 + ic] = (_Float16)cout_w[i];
  }

  const int m = lane & 15;          // A-row within tile / B-col (pixel)
  const int q = lane >> 4;          // k-quarter
  const int q8 = q * 8;
  const int oc16 = wv * 16 + m;     // this lane's A row (oc)

  // ---- preload A fragments for c1 and c2 (resident in VGPRs) ----
  half8 a1f[18], a2f[18];
#pragma unroll
  for (int tap = 0; tap < 9; ++tap)
#pragma unroll
    for (int kb = 0; kb < 2; ++kb) {
      half8 v1, v2;
#pragma unroll
      for (int j = 0; j < 8; ++j) {
        int ic = kb * 32 + q8 + j;
        v1[j] = (_Float16)c1_w[((size_t)oc16 * 64 + ic) * 9 + tap];
        v2[j] = (_Float16)c2_w[((size_t)oc16 * 64 + ic) * 9 + tap];
      }
      a1f[tap * 2 + kb] = v1;
      a2f[tap * 2 + kb] = v2;
    }

  // cin weights: lane = oc (all 64 lanes)
  float cw9[9];
#pragma unroll
  for (int t = 0; t < 9; ++t) cw9[t] = cin_w[lane * 9 + t];
  const float cinb = cin_b[lane];
  const float cob = cout_b[0];

  // pixel coords for MFMA/cout phases (pixel = m)
  const int py = m >> 2, px = m & 3;

  __syncthreads();

  for (int grp = 0; grp < GRPS; ++grp) {
    const int sg = s0 + grp * GS;

    // ---- cin (fp32 VALU): wave wv does sample sg+wv; lane = oc ----
    {
      const float* zp = z + (size_t)(sg + wv) * 16;
      float r[16];
#pragma unroll
      for (int p = 0; p < 16; ++p) r[p] = zp[p];
      float acc[16];
#pragma unroll
      for (int p = 0; p < 16; ++p) acc[p] = 0.0f;
      conv_acc(acc, r, cw9);
      _Float16* dst = hp + wv * SAMP;  // buf A
#pragma unroll
      for (int p = 0; p < 16; ++p)
        dst[((1 + (p >> 2)) * 6 + 1 + (p & 3)) * ROWE + lane] =
            (_Float16)fast_tanh(acc[p] + cinb);
    }
    __syncthreads();

    // ================= c1: bufA -> bufB (MFMA) =================
    {
      f32x4 acc[GS];
#pragma unroll
      for (int g = 0; g < GS; ++g) acc[g] = (f32x4)(0.0f);
      const _Float16* src = hp;  // buf A
#pragma unroll
      for (int tap = 0; tap < 9; ++tap) {
        const int ky = tap / 3, kx = tap % 3;
        const int off = ((py + ky) * 6 + px + kx) * ROWE + q8;
#pragma unroll
        for (int kb = 0; kb < 2; ++kb) {
          half8 a = a1f[tap * 2 + kb];
#pragma unroll
          for (int g = 0; g < GS; ++g) {
            half8 b = *(const half8*)(src + g * SAMP + off + kb * 32);
            acc[g] = __builtin_amdgcn_mfma_f32_16x16x32_f16(a, b, acc[g], 0, 0, 0);
          }
        }
      }
      // epilogue: pixel = m; ocs = wv*16 + q*4 + r
      _Float16* dst = hp + GS * SAMP;  // buf B
      const int pos0 = ((1 + py) * 6 + 1 + px) * ROWE + wv * 16 + q * 4;
      const f32x4 cbv = *(const f32x4*)(c1_b + wv * 16 + q * 4);
#pragma unroll
      for (int g = 0; g < GS; ++g) {
        const float* gp = gb + (size_t)(sg + g) * 256;
        f32x4 gv = *(const f32x4*)(gp + 0 + wv * 16 + q * 4);
        f32x4 bv = *(const f32x4*)(gp + 128 + wv * 16 + q * 4);
        half4_t o;
#pragma unroll
        for (int r = 0; r < 4; ++r)
          o[r] = (_Float16)fast_tanh(gv[r] * (acc[g][r] + cbv[r]) + bv[r]);
        *(half4_t*)(dst + g * SAMP + pos0) = o;
      }
    }
    __syncthreads();

    // ================= c2: bufB -> bufA (MFMA) =================
    {
      f32x4 acc[GS];
#pragma unroll
      for (int g = 0; g < GS; ++g) acc[g] = (f32x4)(0.0f);
      const _Float16* src = hp + GS * SAMP;  // buf B
#pragma unroll
      for (int tap = 0; tap < 9; ++tap) {
        const int ky = tap / 3, kx = tap % 3;
        const int off = ((py + ky) * 6 + px + kx) * ROWE + q8;
#pragma unroll
        for (int kb = 0; kb < 2; ++kb) {
          half8 a = a2f[tap * 2 + kb];
#pragma unroll
          for (int g = 0; g < GS; ++g) {
            half8 b = *(const half8*)(src + g * SAMP + off + kb * 32);
            acc[g] = __builtin_amdgcn_mfma_f32_16x16x32_f16(a, b, acc[g], 0, 0, 0);
          }
        }
      }
      _Float16* dst = hp;  // buf A (h1 dead after c1)
      const int pos0 = ((1 + py) * 6 + 1 + px) * ROWE + wv * 16 + q * 4;
      const f32x4 cbv = *(const f32x4*)(c2_b + wv * 16 + q * 4);
#pragma unroll
      for (int g = 0; g < GS; ++g) {
        const float* gp = gb + (size_t)(sg + g) * 256;
        f32x4 gv = *(const f32x4*)(gp + 64 + wv * 16 + q * 4);
        f32x4 bv = *(const f32x4*)(gp + 192 + wv * 16 + q * 4);
        half4_t o;
#pragma unroll
        for (int r = 0; r < 4; ++r)
          o[r] = (_Float16)fast_tanh(gv[r] * (acc[g][r] + cbv[r]) + bv[r]);
        *(half4_t*)(dst + g * SAMP + pos0) = o;
      }
    }
    __syncthreads();

    // ---- cout: wave wv does sample sg+wv; lane = (icq, pixel) ----
    {
      const int icq = q;  // 4 ic-quarters of 16 ics; pixel = m
      const _Float16* src = hp + wv * SAMP;
      float acc = 0.0f;
#pragma unroll
      for (int tap = 0; tap < 9; ++tap) {
        const int ky = tap / 3, kx = tap % 3;
        const int pos = (py + ky) * 6 + px + kx;
        half8 hv0 = *(const half8*)(src + pos * ROWE + icq * 16);
        half8 hv1 = *(const half8*)(src + pos * ROWE + icq * 16 + 8);
        half8 wv0 = *(const half8*)(cwl + tap * 64 + icq * 16);
        half8 wv1 = *(const half8*)(cwl + tap * 64 + icq * 16 + 8);
#pragma unroll
        for (int j = 0; j < 4; ++j) {
          half2_t h2a = {hv0[2 * j], hv0[2 * j + 1]};
          half2_t w2a = {wv0[2 * j], wv0[2 * j + 1]};
          half2_t h2b = {hv1[2 * j], hv1[2 * j + 1]};
          half2_t w2b = {wv1[2 * j], wv1[2 * j + 1]};
#if __has_builtin(__builtin_amdgcn_fdot2)
          acc = __builtin_amdgcn_fdot2(h2a, w2a, acc, false);
          acc = __builtin_amdgcn_fdot2(h2b, w2b, acc, false);
#else
          acc += (float)h2a[0] * (float)w2a[0] + (float)h2a[1] * (float)w2a[1];
          acc += (float)h2b[0] * (float)w2b[0] + (float)h2b[1] * (float)w2b[1];
#endif
        }
      }
      acc += __shfl_xor(acc, 16);
      acc += __shfl_xor(acc, 32);
      if (q == 0) out[(size_t)(sg + wv) * 16 + m] = acc + cob;
    }
    __syncthreads();
  }
}

// ---------------------------------------------------------------------------
extern "C" void kernel_launch(void* const* d_in, const int* in_sizes, int n_in,
                              void* d_out, int out_size, void* d_ws, size_t ws_size,
                              hipStream_t stream) {
  const float* tt     = (const float*)d_in[0];
  const float* z      = (const float*)d_in[1];
  const float* mu     = (const float*)d_in[2];
  const float* W1     = (const float*)d_in[3];
  const float* b1     = (const float*)d_in[4];
  const float* W2     = (const float*)d_in[5];
  const float* b2     = (const float*)d_in[6];
  const float* Wg     = (const float*)d_in[7];
  const float* bg     = (const float*)d_in[8];
  const float* cin_w  = (const float*)d_in[9];
  const float* cin_b  = (const float*)d_in[10];
  const float* c1_w   = (const float*)d_in[11];
  const float* c1_b   = (const float*)d_in[12];
  const float* c2_w   = (const float*)d_in[13];
  const float* c2_b   = (const float*)d_in[14];
  const float* cout_w = (const float*)d_in[15];
  const float* cout_b = (const float*)d_in[16];

  float* out = (float*)d_out;
  float* gbo = (float*)d_ws;  // (B, 256) fp32 gates

  mlp_kernel<<<NB / 16, 128, 0, stream>>>(tt, mu, W1, b1, W2, b2, Wg, bg, gbo);
  conv_kernel<<<NB / (GRPS * GS), 256, 0, stream>>>(z, gbo, cin_w, cin_b, c1_w, c1_b,
                                                    c2_w, c2_b, cout_w, cout_b, out);
}

// Round 3
// 260.689 us; speedup vs baseline: 4.6871x; 1.3779x over previous
//
#include <hip/hip_runtime.h>
#include <cstdint>
#include <cstddef>

// ---------------------------------------------------------------------------
// AffineModulatedLatentODEFunc
//   kernel 0: prep  — transpose/pack all weights to f16 in ws
//   kernel 1: MLP   — f16 MFMA (A=W^T, B=acts, D[unit][sample]) -> gb f16
//   kernel 2: conv  — f16 MFMA mid layers, e(pos)-swizzled LDS (bank-conflict fix)
// ---------------------------------------------------------------------------

#define NB 32768

typedef _Float16 half8   __attribute__((ext_vector_type(8)));
typedef _Float16 half4_t __attribute__((ext_vector_type(4)));
typedef _Float16 half2_t __attribute__((ext_vector_type(2)));
typedef float    f32x4   __attribute__((ext_vector_type(4)));

__device__ __forceinline__ float fast_tanh(float x) {
  // tanh(x) = 1 - 2/(e^{2x}+1); inf-safe both directions, 5 VALU ops
  float e = __expf(2.0f * x);
  return 1.0f - __fdividef(2.0f, e + 1.0f);
}

__device__ __forceinline__ float elu_f(float v) {
  return v > 0.0f ? v : (__expf(v) - 1.0f);
}

// 3x3 "same" conv on a 4x4 tile, fully unrolled -> 100 FMAs
__device__ __forceinline__ void conv_acc(float acc[16], const float r[16], const float w[9]) {
#pragma unroll
  for (int y = 0; y < 4; ++y)
#pragma unroll
    for (int x = 0; x < 4; ++x)
#pragma unroll
      for (int ky = 0; ky < 3; ++ky) {
        int iy = y + ky - 1;
        if (iy < 0 || iy >= 4) continue;
#pragma unroll
        for (int kx = 0; kx < 3; ++kx) {
          int ix = x + kx - 1;
          if (ix < 0 || ix >= 4) continue;
          acc[y * 4 + x] += w[ky * 3 + kx] * r[iy * 4 + ix];
        }
      }
}

// ---------------------------------------------------------------------------
// prep: pack weights to f16.
//  W1t[128][32], W2t[128][128], Wgt[256][128]  (row = output unit, col = k)
//  c1t/c2t[18][64][32]: [tap*2+kb][oc][ic-kb*32]  (A-fragment layout)
// ---------------------------------------------------------------------------
__global__ __launch_bounds__(256) void prep_kernel(
    const float* __restrict__ W1, const float* __restrict__ W2,
    const float* __restrict__ Wg, const float* __restrict__ c1w,
    const float* __restrict__ c2w, _Float16* __restrict__ wt) {
  int idx = blockIdx.x * 256 + threadIdx.x;
  _Float16* W1t = wt;            // 4096
  _Float16* W2t = W1t + 4096;    // 16384
  _Float16* Wgt = W2t + 16384;   // 32768
  _Float16* c1t = Wgt + 32768;   // 36864
  _Float16* c2t = c1t + 36864;   // 36864
  if (idx < 4096) {
    int n = idx >> 5, k = idx & 31;
    W1t[idx] = (_Float16)W1[k * 128 + n];
  } else if (idx < 20480) {
    int i = idx - 4096;
    int n = i >> 7, k = i & 127;
    W2t[i] = (_Float16)W2[k * 128 + n];
  } else if (idx < 53248) {
    int i = idx - 20480;
    int n = i >> 7, k = i & 127;
    Wgt[i] = (_Float16)Wg[k * 256 + n];
  } else if (idx < 90112) {
    int i = idx - 53248;
    int ts = i >> 11, r = i & 2047, oc = r >> 5, icw = r & 31;
    int tap = ts >> 1, kb = ts & 1, ic = kb * 32 + icw;
    c1t[i] = (_Float16)c1w[(oc * 64 + ic) * 9 + tap];
  } else if (idx < 126976) {
    int i = idx - 90112;
    int ts = i >> 11, r = i & 2047, oc = r >> 5, icw = r & 31;
    int tap = ts >> 1, kb = ts & 1, ic = kb * 32 + icw;
    c2t[i] = (_Float16)c2w[(oc * 64 + ic) * 9 + tap];
  }
}

// ---------------------------------------------------------------------------
// MLP: 256 thr = 4 waves, 16 samples/wave. D[unit][sample] layout:
//   A = Wt rows (units), B = activations (col = sample = lane&15).
// ---------------------------------------------------------------------------
__global__ __launch_bounds__(256) void mlp_kernel(
    const float* __restrict__ tt, const float* __restrict__ mu,
    const _Float16* __restrict__ wt,
    const float* __restrict__ b1, const float* __restrict__ b2,
    const float* __restrict__ bg, _Float16* __restrict__ gbf) {
  const int tid = threadIdx.x;
  const int lane = tid & 63;
  const int wv = tid >> 6;
  const int m = lane & 15, q = lane >> 4;
  const int q4 = q * 4, q8 = q * 8;
  const int s = blockIdx.x * 64 + wv * 16 + m;

  const _Float16* W1t = wt;
  const _Float16* W2t = W1t + 4096;
  const _Float16* Wgt = W2t + 16384;

  __shared__ __align__(16) _Float16 xi_lds[4][16 * 136];
  _Float16* xw = &xi_lds[wv][0];

  // embedding B-frag: features 8q..8q+7 of sample s  (q=0: t, q>0: mu[q-1])
  const float TM = 31.41592653589793f;
  float base = (q == 0) ? tt[s] : mu[(size_t)s * 3 + (q - 1)];
  half8 xb;
  float fr = 1.0f;
#pragma unroll
  for (int j = 0; j < 4; ++j) {
    float sn, cs;
    __sincosf(base * fr, &sn, &cs);
    xb[j] = (_Float16)sn;
    xb[4 + j] = (_Float16)cs;
    fr *= (1.0f / TM);
  }

  // ---- L1: h = elu(x@W1+b1) ----
#pragma unroll
  for (int nt = 0; nt < 8; ++nt) {
    half8 af = *(const half8*)(W1t + (nt * 16 + m) * 32 + q8);
    f32x4 c = __builtin_amdgcn_mfma_f32_16x16x32_f16(af, xb, (f32x4)(0.0f), 0, 0, 0);
    f32x4 bv = *(const f32x4*)(b1 + nt * 16 + q4);
    half4_t o;
#pragma unroll
    for (int r = 0; r < 4; ++r) o[r] = (_Float16)elu_f(c[r] + bv[r]);
    *(half4_t*)(xw + m * 136 + nt * 16 + q4) = o;  // [sample][unit]
  }
  // same-wave LDS bounce (no barrier needed)
  half8 xf0 = *(const half8*)(xw + m * 136 + 0 + q8);
  half8 xf1 = *(const half8*)(xw + m * 136 + 32 + q8);
  half8 xf2 = *(const half8*)(xw + m * 136 + 64 + q8);
  half8 xf3 = *(const half8*)(xw + m * 136 + 96 + q8);

  // ---- L2: xi = elu(h@W2+b2) ----
#pragma unroll
  for (int nt = 0; nt < 8; ++nt) {
    const _Float16* wp = W2t + (nt * 16 + m) * 128;
    f32x4 c = (f32x4)(0.0f);
    c = __builtin_amdgcn_mfma_f32_16x16x32_f16(*(const half8*)(wp + q8), xf0, c, 0, 0, 0);
    c = __builtin_amdgcn_mfma_f32_16x16x32_f16(*(const half8*)(wp + 32 + q8), xf1, c, 0, 0, 0);
    c = __builtin_amdgcn_mfma_f32_16x16x32_f16(*(const half8*)(wp + 64 + q8), xf2, c, 0, 0, 0);
    c = __builtin_amdgcn_mfma_f32_16x16x32_f16(*(const half8*)(wp + 96 + q8), xf3, c, 0, 0, 0);
    f32x4 bv = *(const f32x4*)(b2 + nt * 16 + q4);
    half4_t o;
#pragma unroll
    for (int r = 0; r < 4; ++r) o[r] = (_Float16)elu_f(c[r] + bv[r]);
    *(half4_t*)(xw + m * 136 + nt * 16 + q4) = o;
  }
  half8 yf0 = *(const half8*)(xw + m * 136 + 0 + q8);
  half8 yf1 = *(const half8*)(xw + m * 136 + 32 + q8);
  half8 yf2 = *(const half8*)(xw + m * 136 + 64 + q8);
  half8 yf3 = *(const half8*)(xw + m * 136 + 96 + q8);

  // ---- L3: gb = xi@Wg + bg ; lane stores 4 consecutive units of sample s ----
#pragma unroll
  for (int ut = 0; ut < 16; ++ut) {
    const _Float16* wp = Wgt + (ut * 16 + m) * 128;
    f32x4 c = (f32x4)(0.0f);
    c = __builtin_amdgcn_mfma_f32_16x16x32_f16(*(const half8*)(wp + q8), yf0, c, 0, 0, 0);
    c = __builtin_amdgcn_mfma_f32_16x16x32_f16(*(const half8*)(wp + 32 + q8), yf1, c, 0, 0, 0);
    c = __builtin_amdgcn_mfma_f32_16x16x32_f16(*(const half8*)(wp + 64 + q8), yf2, c, 0, 0, 0);
    c = __builtin_amdgcn_mfma_f32_16x16x32_f16(*(const half8*)(wp + 96 + q8), yf3, c, 0, 0, 0);
    f32x4 bv = *(const f32x4*)(bg + ut * 16 + q4);
    half4_t o;
#pragma unroll
    for (int r = 0; r < 4; ++r) o[r] = (_Float16)(c[r] + bv[r]);
    *(half4_t*)(gbf + (size_t)s * 256 + ut * 16 + q4) = o;
  }
}

// ---------------------------------------------------------------------------
// conv kernel. LDS h tile: [pos 0..35][64 ic f16], 144 B/pos; the two 64B
// ic-halves are swapped iff e(pos) = ((pos/6)&1) ^ ((pos>>2)&1)  -> all
// ds_read_b128 8-lane phases hit 8 distinct 4-bank granules (conflict-free).
// ---------------------------------------------------------------------------
#define ROWE 72            // halfs per position
#define SAMP 2592          // 36*72 halfs per sample buffer
#define GS 4
#define GRPS 16

__device__ __forceinline__ void mid_layer_mfma(
    const _Float16* __restrict__ src, _Float16* __restrict__ dst,
    const half8 af[18], const f32x4 cbv,
    const _Float16* __restrict__ gbase, int goff,
    int wv, int q, int py, int px) {
  f32x4 acc[GS];
#pragma unroll
  for (int g = 0; g < GS; ++g) acc[g] = (f32x4)(0.0f);
#pragma unroll
  for (int tap = 0; tap < 9; ++tap) {
    const int ky = tap / 3, kx = tap % 3;
    const int row = py + ky;
    const int pos = row * 6 + px + kx;
    const int e = (row ^ (pos >> 2)) & 1;
    const int o0 = pos * ROWE + q * 8 + e * 32;        // kb=0 chunk
    const int o1 = pos * ROWE + q * 8 + 32 - e * 32;   // kb=1 chunk
#pragma unroll
    for (int g = 0; g < GS; ++g) {
      half8 bb = *(const half8*)(src + g * SAMP + o0);
      acc[g] = __builtin_amdgcn_mfma_f32_16x16x32_f16(af[tap * 2 + 0], bb, acc[g], 0, 0, 0);
    }
#pragma unroll
    for (int g = 0; g < GS; ++g) {
      half8 bb = *(const half8*)(src + g * SAMP + o1);
      acc[g] = __builtin_amdgcn_mfma_f32_16x16x32_f16(af[tap * 2 + 1], bb, acc[g], 0, 0, 0);
    }
  }
  // epilogue: pixel = m (py,px); ocs = wv*16 + q*4 + r
  const int icb = wv * 16 + q * 4;
  const int row = 1 + py;
  const int pos = row * 6 + 1 + px;
  const int e = (row ^ (pos >> 2)) & 1;
  const int daddr = pos * ROWE + (((icb >> 5) ^ e) << 5) + (icb & 31);
#pragma unroll
  for (int g = 0; g < GS; ++g) {
    const _Float16* gp = gbase + g * 256 + goff + icb;
    half4_t gv = *(const half4_t*)(gp);
    half4_t bv = *(const half4_t*)(gp + 128);
    half4_t o;
#pragma unroll
    for (int r = 0; r < 4; ++r)
      o[r] = (_Float16)fast_tanh((float)gv[r] * (acc[g][r] + cbv[r]) + (float)bv[r]);
    *(half4_t*)(dst + g * SAMP + daddr) = o;
  }
}

__global__ __launch_bounds__(256, 2) void conv_kernel(
    const float* __restrict__ z, const _Float16* __restrict__ gbf,
    const float* __restrict__ cin_w, const float* __restrict__ cin_b,
    const _Float16* __restrict__ c1t, const _Float16* __restrict__ c2t,
    const float* __restrict__ c1_b, const float* __restrict__ c2_b,
    const float* __restrict__ cout_w, const float* __restrict__ cout_b,
    float* __restrict__ out) {
  const int tid = threadIdx.x;
  const int lane = tid & 63;
  const int wv = tid >> 6;
  const int s0 = blockIdx.x * (GRPS * GS);

  __shared__ __align__(16) _Float16 hp[2 * GS * SAMP];
  __shared__ __align__(16) _Float16 cwl[9 * 64];

  for (int i = tid; i < (2 * GS * SAMP) / 2; i += 256) ((uint32_t*)hp)[i] = 0u;
  for (int i = tid; i < 576; i += 256) {
    int ic = i / 9, tap = i % 9;
    cwl[tap * 64 + ic] = (_Float16)cout_w[i];
  }

  const int m = lane & 15, q = lane >> 4, q8 = q * 8, q4 = q * 4;
  const int py = m >> 2, px = m & 3;

  // resident A-frags (f16, pre-packed by prep) — 36 coalesced dwordx4
  half8 a1f[18], a2f[18];
#pragma unroll
  for (int t = 0; t < 18; ++t) {
    a1f[t] = *(const half8*)(c1t + t * 2048 + (wv * 16 + m) * 32 + q8);
    a2f[t] = *(const half8*)(c2t + t * 2048 + (wv * 16 + m) * 32 + q8);
  }

  float cw9[9];
#pragma unroll
  for (int t = 0; t < 9; ++t) cw9[t] = cin_w[lane * 9 + t];
  const float cinb = cin_b[lane];
  const float cob = cout_b[0];
  const f32x4 cb1 = *(const f32x4*)(c1_b + wv * 16 + q4);
  const f32x4 cb2 = *(const f32x4*)(c2_b + wv * 16 + q4);

  __syncthreads();

  for (int grp = 0; grp < GRPS; ++grp) {
    const int sg = s0 + grp * GS;
    const _Float16* gbase = gbf + (size_t)sg * 256;

    // ---- cin (fp32): wave wv -> sample sg+wv; lane = oc ----
    {
      const float* zp = z + (size_t)(sg + wv) * 16;
      float r[16], acc[16];
#pragma unroll
      for (int p = 0; p < 16; ++p) { r[p] = zp[p]; acc[p] = 0.0f; }
      conv_acc(acc, r, cw9);
      _Float16* dst = hp + wv * SAMP;
      const int ics = lane & 31, ich = lane >> 5;
#pragma unroll
      for (int p = 0; p < 16; ++p) {
        int row = 1 + (p >> 2);
        int pos = row * 6 + 1 + (p & 3);
        int e = (row ^ (pos >> 2)) & 1;
        dst[pos * ROWE + ((ich ^ e) << 5) + ics] = (_Float16)fast_tanh(acc[p] + cinb);
      }
    }
    __syncthreads();

    // ---- c1: bufA -> bufB ----
    mid_layer_mfma(hp, hp + GS * SAMP, a1f, cb1, gbase, 0, wv, q, py, px);
    __syncthreads();

    // ---- c2: bufB -> bufA ----
    mid_layer_mfma(hp + GS * SAMP, hp, a2f, cb2, gbase, 64, wv, q, py, px);
    __syncthreads();

    // ---- cout: wave wv -> sample sg+wv; lane = (ic-quarter q, pixel m) ----
    {
      const _Float16* src = hp + wv * SAMP;
      const int c32 = q >> 1;
      const int coff = (q * 16) & 31;
      float acc = 0.0f;
#pragma unroll
      for (int tap = 0; tap < 9; ++tap) {
        const int ky = tap / 3, kx = tap % 3;
        const int row = py + ky;
        const int pos = row * 6 + px + kx;
        const int e = (row ^ (pos >> 2)) & 1;
        const _Float16* sp = src + pos * ROWE + ((c32 ^ e) << 5) + coff;
        half8 hv0 = *(const half8*)(sp);
        half8 hv1 = *(const half8*)(sp + 8);
        half8 wv0 = *(const half8*)(cwl + tap * 64 + q * 16);
        half8 wv1 = *(const half8*)(cwl + tap * 64 + q * 16 + 8);
#pragma unroll
        for (int j = 0; j < 4; ++j) {
          half2_t h2a = {hv0[2 * j], hv0[2 * j + 1]};
          half2_t w2a = {wv0[2 * j], wv0[2 * j + 1]};
          half2_t h2b = {hv1[2 * j], hv1[2 * j + 1]};
          half2_t w2b = {wv1[2 * j], wv1[2 * j + 1]};
#if __has_builtin(__builtin_amdgcn_fdot2)
          acc = __builtin_amdgcn_fdot2(h2a, w2a, acc, false);
          acc = __builtin_amdgcn_fdot2(h2b, w2b, acc, false);
#else
          acc += (float)h2a[0] * (float)w2a[0] + (float)h2a[1] * (float)w2a[1];
          acc += (float)h2b[0] * (float)w2b[0] + (float)h2b[1] * (float)w2b[1];
#endif
        }
      }
      acc += __shfl_xor(acc, 16);
      acc += __shfl_xor(acc, 32);
      if (q == 0) out[(size_t)(sg + wv) * 16 + m] = acc + cob;
    }
    __syncthreads();
  }
}

// ---------------------------------------------------------------------------
extern "C" void kernel_launch(void* const* d_in, const int* in_sizes, int n_in,
                              void* d_out, int out_size, void* d_ws, size_t ws_size,
                              hipStream_t stream) {
  const float* tt     = (const float*)d_in[0];
  const float* z      = (const float*)d_in[1];
  const float* mu     = (const float*)d_in[2];
  const float* W1     = (const float*)d_in[3];
  const float* b1     = (const float*)d_in[4];
  const float* W2     = (const float*)d_in[5];
  const float* b2     = (const float*)d_in[6];
  const float* Wg     = (const float*)d_in[7];
  const float* bg     = (const float*)d_in[8];
  const float* cin_w  = (const float*)d_in[9];
  const float* cin_b  = (const float*)d_in[10];
  const float* c1_w   = (const float*)d_in[11];
  const float* c1_b   = (const float*)d_in[12];
  const float* c2_w   = (const float*)d_in[13];
  const float* c2_b   = (const float*)d_in[14];
  const float* cout_w = (const float*)d_in[15];
  const float* cout_b = (const float*)d_in[16];

  float* out = (float*)d_out;
  _Float16* gbf = (_Float16*)d_ws;                 // 32768*256 f16 = 16 MB
  _Float16* wt  = gbf + (size_t)NB * 256;          // packed weights
  _Float16* W1t = wt;
  _Float16* W2t = W1t + 4096;
  _Float16* Wgt = W2t + 16384;
  _Float16* c1t = Wgt + 32768;
  _Float16* c2t = c1t + 36864;

  prep_kernel<<<496, 256, 0, stream>>>(W1, W2, Wg, c1_w, c2_w, wt);
  mlp_kernel<<<NB / 64, 256, 0, stream>>>(tt, mu, wt, b1, b2, bg, gbf);
  conv_kernel<<<NB / (GRPS * GS), 256, 0, stream>>>(z, gbf, cin_w, cin_b,
                                                    c1t, c2t, c1_b, c2_b,
                                                    cout_w, cout_b, out);
}

// Round 4
// 226.574 us; speedup vs baseline: 5.3929x; 1.1506x over previous
//
#include <hip/hip_runtime.h>
#include <cstdint>
#include <cstddef>

// ---------------------------------------------------------------------------
// AffineModulatedLatentODEFunc — fused single-kernel version
//   kernel 0: prep — pack all weights to f16 in MFMA fragment order (ws)
//   kernel 1: fused — per block of 64 samples:
//       phase 0: MLP via f16 MFMA -> gb in LDS
//       phase 1: 16 groups x {cin (VALU) -> c1 (MFMA) -> c2 (MFMA) -> cout (fdot2)}
//   LDS h tiles use the e(pos) 64B-chunk swizzle (bank-conflict fix, round 3)
// ---------------------------------------------------------------------------

#define NB 32768

typedef _Float16 half8   __attribute__((ext_vector_type(8)));
typedef _Float16 half4_t __attribute__((ext_vector_type(4)));
typedef _Float16 half2_t __attribute__((ext_vector_type(2)));
typedef float    f32x4   __attribute__((ext_vector_type(4)));

__device__ __forceinline__ float fast_tanh(float x) {
  float e = __expf(2.0f * x);
  return 1.0f - __fdividef(2.0f, e + 1.0f);
}

__device__ __forceinline__ float elu_f(float v) {
  return v > 0.0f ? v : (__expf(v) - 1.0f);
}

// 3x3 "same" conv on a 4x4 tile, fully unrolled -> 100 FMAs
__device__ __forceinline__ void conv_acc(float acc[16], const float r[16], const float w[9]) {
#pragma unroll
  for (int y = 0; y < 4; ++y)
#pragma unroll
    for (int x = 0; x < 4; ++x)
#pragma unroll
      for (int ky = 0; ky < 3; ++ky) {
        int iy = y + ky - 1;
        if (iy < 0 || iy >= 4) continue;
#pragma unroll
        for (int kx = 0; kx < 3; ++kx) {
          int ix = x + kx - 1;
          if (ix < 0 || ix >= 4) continue;
          acc[y * 4 + x] += w[ky * 3 + kx] * r[iy * 4 + ix];
        }
      }
}

// ---------------------------------------------------------------------------
// prep: pack weights to f16, ALL in MFMA A-fragment order.
//  W1f[nt][lane][8]        : nt<8,  val = W1[k*128+n], n=nt*16+(lane&15), k=(lane>>4)*8+j
//  W2f[nt*4+kb][lane][8]   : val = W2[k*128+n], k=kb*32+(lane>>4)*8+j
//  Wgf[ut*4+kb][lane][8]   : val = Wg[k*256+n], n=ut*16+(lane&15)
//  c1t/c2t[18][64][32]     : [tap*2+kb][oc][ic-kb*32]
// ---------------------------------------------------------------------------
__global__ __launch_bounds__(256) void prep_kernel(
    const float* __restrict__ W1, const float* __restrict__ W2,
    const float* __restrict__ Wg, const float* __restrict__ c1w,
    const float* __restrict__ c2w, _Float16* __restrict__ wt) {
  int idx = blockIdx.x * 256 + threadIdx.x;
  _Float16* W1f = wt;            // 4096
  _Float16* W2f = W1f + 4096;    // 16384
  _Float16* Wgf = W2f + 16384;   // 32768
  _Float16* c1t = Wgf + 32768;   // 36864
  _Float16* c2t = c1t + 36864;   // 36864
  if (idx < 4096) {
    int i = idx, j = i & 7, lane = (i >> 3) & 63, nt = i >> 9;
    int n = nt * 16 + (lane & 15), k = (lane >> 4) * 8 + j;
    W1f[i] = (_Float16)W1[k * 128 + n];
  } else if (idx < 20480) {
    int i = idx - 4096, j = i & 7, lane = (i >> 3) & 63, r = i >> 9;
    int kb = r & 3, nt = r >> 2;
    int n = nt * 16 + (lane & 15), k = kb * 32 + (lane >> 4) * 8 + j;
    W2f[i] = (_Float16)W2[k * 128 + n];
  } else if (idx < 53248) {
    int i = idx - 20480, j = i & 7, lane = (i >> 3) & 63, r = i >> 9;
    int kb = r & 3, ut = r >> 2;
    int n = ut * 16 + (lane & 15), k = kb * 32 + (lane >> 4) * 8 + j;
    Wgf[i] = (_Float16)Wg[k * 256 + n];
  } else if (idx < 90112) {
    int i = idx - 53248;
    int ts = i >> 11, r = i & 2047, oc = r >> 5, icw = r & 31;
    int tap = ts >> 1, kb = ts & 1, ic = kb * 32 + icw;
    c1t[i] = (_Float16)c1w[(oc * 64 + ic) * 9 + tap];
  } else if (idx < 126976) {
    int i = idx - 90112;
    int ts = i >> 11, r = i & 2047, oc = r >> 5, icw = r & 31;
    int tap = ts >> 1, kb = ts & 1, ic = kb * 32 + icw;
    c2t[i] = (_Float16)c2w[(oc * 64 + ic) * 9 + tap];
  }
}

// ---------------------------------------------------------------------------
// fused kernel
// ---------------------------------------------------------------------------
#define ROWE 72            // halfs per padded position
#define SAMP 2592          // 36*72 halfs per sample buffer
#define GS 4
#define GRPS 16
#define GBROW 264          // gb_lds row stride (halfs), conflict-free

__device__ __forceinline__ void mid_layer_mfma(
    const _Float16* __restrict__ src, _Float16* __restrict__ dst,
    const half8 af[18], const f32x4 cbv,
    const _Float16* __restrict__ gbase, int goff,
    int wv, int q, int py, int px) {
  f32x4 acc[GS];
#pragma unroll
  for (int g = 0; g < GS; ++g) acc[g] = (f32x4)(0.0f);
#pragma unroll
  for (int tap = 0; tap < 9; ++tap) {
    const int ky = tap / 3, kx = tap % 3;
    const int row = py + ky;
    const int pos = row * 6 + px + kx;
    const int e = (row ^ (pos >> 2)) & 1;
    const int o0 = pos * ROWE + q * 8 + e * 32;        // kb=0 chunk
    const int o1 = pos * ROWE + q * 8 + 32 - e * 32;   // kb=1 chunk
#pragma unroll
    for (int g = 0; g < GS; ++g) {
      half8 bb = *(const half8*)(src + g * SAMP + o0);
      acc[g] = __builtin_amdgcn_mfma_f32_16x16x32_f16(af[tap * 2 + 0], bb, acc[g], 0, 0, 0);
    }
#pragma unroll
    for (int g = 0; g < GS; ++g) {
      half8 bb = *(const half8*)(src + g * SAMP + o1);
      acc[g] = __builtin_amdgcn_mfma_f32_16x16x32_f16(af[tap * 2 + 1], bb, acc[g], 0, 0, 0);
    }
  }
  const int icb = wv * 16 + q * 4;
  const int row = 1 + py;
  const int pos = row * 6 + 1 + px;
  const int e = (row ^ (pos >> 2)) & 1;
  const int daddr = pos * ROWE + (((icb >> 5) ^ e) << 5) + (icb & 31);
#pragma unroll
  for (int g = 0; g < GS; ++g) {
    const _Float16* gp = gbase + g * GBROW + goff + icb;
    half4_t gv = *(const half4_t*)(gp);
    half4_t bv = *(const half4_t*)(gp + 128);
    half4_t o;
#pragma unroll
    for (int r = 0; r < 4; ++r)
      o[r] = (_Float16)fast_tanh((float)gv[r] * (acc[g][r] + cbv[r]) + (float)bv[r]);
    *(half4_t*)(dst + g * SAMP + daddr) = o;
  }
}

__global__ __launch_bounds__(256, 2) void fused_kernel(
    const float* __restrict__ tt, const float* __restrict__ mu,
    const float* __restrict__ z, const _Float16* __restrict__ wt,
    const float* __restrict__ b1, const float* __restrict__ b2,
    const float* __restrict__ bg,
    const float* __restrict__ cin_w, const float* __restrict__ cin_b,
    const float* __restrict__ c1_b, const float* __restrict__ c2_b,
    const float* __restrict__ cout_w, const float* __restrict__ cout_b,
    float* __restrict__ out) {
  const int tid = threadIdx.x;
  const int lane = tid & 63;
  const int wv = tid >> 6;
  const int m = lane & 15, q = lane >> 4, q8 = q * 8, q4 = q * 4;
  const int py = m >> 2, px = m & 3;
  const int s0 = blockIdx.x * (GRPS * GS);   // 64 samples per block

  const _Float16* W1f = wt;
  const _Float16* W2f = W1f + 4096;
  const _Float16* Wgf = W2f + 16384;
  const _Float16* c1t = Wgf + 32768;
  const _Float16* c2t = c1t + 36864;

  __shared__ __align__(16) _Float16 hp[2 * GS * SAMP];      // 41472 B
  __shared__ __align__(16) _Float16 gb_lds[64 * GBROW];     // 33792 B
  __shared__ __align__(16) _Float16 cwl[9 * 64];            // 1152 B

  // ===================== Phase 0: MLP for 64 samples =====================
  {
    const int sl = wv * 16 + m;              // block-local sample
    const int s = s0 + sl;
    _Float16* xw = hp + wv * SAMP;           // per-wave bounce buffer (2176<=2592)

    const float TM = 31.41592653589793f;
    float base = (q == 0) ? tt[s] : mu[(size_t)s * 3 + (q - 1)];
    half8 xb;
    float fr = 1.0f;
#pragma unroll
    for (int j = 0; j < 4; ++j) {
      float sn, cs;
      __sincosf(base * fr, &sn, &cs);
      xb[j] = (_Float16)sn;
      xb[4 + j] = (_Float16)cs;
      fr *= (1.0f / TM);
    }

    // L1: h = elu(x@W1+b1)
#pragma unroll
    for (int nt = 0; nt < 8; ++nt) {
      half8 af = *(const half8*)(W1f + (nt * 64 + lane) * 8);
      f32x4 c = __builtin_amdgcn_mfma_f32_16x16x32_f16(af, xb, (f32x4)(0.0f), 0, 0, 0);
      f32x4 bv = *(const f32x4*)(b1 + nt * 16 + q4);
      half4_t o;
#pragma unroll
      for (int r = 0; r < 4; ++r) o[r] = (_Float16)elu_f(c[r] + bv[r]);
      *(half4_t*)(xw + m * 136 + nt * 16 + q4) = o;
    }
    half8 xf0 = *(const half8*)(xw + m * 136 + 0 + q8);
    half8 xf1 = *(const half8*)(xw + m * 136 + 32 + q8);
    half8 xf2 = *(const half8*)(xw + m * 136 + 64 + q8);
    half8 xf3 = *(const half8*)(xw + m * 136 + 96 + q8);

    // L2: xi = elu(h@W2+b2)
#pragma unroll
    for (int nt = 0; nt < 8; ++nt) {
      const _Float16* wp = W2f + (nt * 4) * 512 + lane * 8;
      f32x4 c = (f32x4)(0.0f);
      c = __builtin_amdgcn_mfma_f32_16x16x32_f16(*(const half8*)(wp), xf0, c, 0, 0, 0);
      c = __builtin_amdgcn_mfma_f32_16x16x32_f16(*(const half8*)(wp + 512), xf1, c, 0, 0, 0);
      c = __builtin_amdgcn_mfma_f32_16x16x32_f16(*(const half8*)(wp + 1024), xf2, c, 0, 0, 0);
      c = __builtin_amdgcn_mfma_f32_16x16x32_f16(*(const half8*)(wp + 1536), xf3, c, 0, 0, 0);
      f32x4 bv = *(const f32x4*)(b2 + nt * 16 + q4);
      half4_t o;
#pragma unroll
      for (int r = 0; r < 4; ++r) o[r] = (_Float16)elu_f(c[r] + bv[r]);
      *(half4_t*)(xw + m * 136 + nt * 16 + q4) = o;
    }
    half8 yf0 = *(const half8*)(xw + m * 136 + 0 + q8);
    half8 yf1 = *(const half8*)(xw + m * 136 + 32 + q8);
    half8 yf2 = *(const half8*)(xw + m * 136 + 64 + q8);
    half8 yf3 = *(const half8*)(xw + m * 136 + 96 + q8);

    // L3: gb = xi@Wg + bg -> gb_lds
#pragma unroll
    for (int ut = 0; ut < 16; ++ut) {
      const _Float16* wp = Wgf + (ut * 4) * 512 + lane * 8;
      f32x4 c = (f32x4)(0.0f);
      c = __builtin_amdgcn_mfma_f32_16x16x32_f16(*(const half8*)(wp), yf0, c, 0, 0, 0);
      c = __builtin_amdgcn_mfma_f32_16x16x32_f16(*(const half8*)(wp + 512), yf1, c, 0, 0, 0);
      c = __builtin_amdgcn_mfma_f32_16x16x32_f16(*(const half8*)(wp + 1024), yf2, c, 0, 0, 0);
      c = __builtin_amdgcn_mfma_f32_16x16x32_f16(*(const half8*)(wp + 1536), yf3, c, 0, 0, 0);
      f32x4 bv = *(const f32x4*)(bg + ut * 16 + q4);
      half4_t o;
#pragma unroll
      for (int r = 0; r < 4; ++r) o[r] = (_Float16)(c[r] + bv[r]);
      *(half4_t*)(gb_lds + sl * GBROW + ut * 16 + q4) = o;
    }
  }

  // resident conv A-frags (loaded here to overlap with barrier/zero-init)
  half8 a1f[18], a2f[18];
#pragma unroll
  for (int t = 0; t < 18; ++t) {
    a1f[t] = *(const half8*)(c1t + t * 2048 + (wv * 16 + m) * 32 + q8);
    a2f[t] = *(const half8*)(c2t + t * 2048 + (wv * 16 + m) * 32 + q8);
  }
  float cw9[9];
#pragma unroll
  for (int t = 0; t < 9; ++t) cw9[t] = cin_w[lane * 9 + t];
  const float cinb = cin_b[lane];
  const float cob = cout_b[0];
  const f32x4 cb1 = *(const f32x4*)(c1_b + wv * 16 + q4);
  const f32x4 cb2 = *(const f32x4*)(c2_b + wv * 16 + q4);

  __syncthreads();   // MLP done (hp scratch free, gb_lds complete)

  // zero hp (borders must be 0), stage cout weights
  for (int i = tid; i < (2 * GS * SAMP) / 2; i += 256) ((uint32_t*)hp)[i] = 0u;
  for (int i = tid; i < 576; i += 256) {
    int ic = i / 9, tap = i % 9;
    cwl[tap * 64 + ic] = (_Float16)cout_w[i];
  }
  __syncthreads();

  // ===================== Phase 1: conv groups =====================
  for (int grp = 0; grp < GRPS; ++grp) {
    const int sg = s0 + grp * GS;
    const _Float16* gbase = gb_lds + (size_t)(grp * GS) * GBROW;

    // ---- cin (fp32): wave wv -> sample sg+wv; lane = oc ----
    {
      const float* zp = z + (size_t)(sg + wv) * 16;
      float r[16], acc[16];
#pragma unroll
      for (int p = 0; p < 16; ++p) { r[p] = zp[p]; acc[p] = 0.0f; }
      conv_acc(acc, r, cw9);
      _Float16* dst = hp + wv * SAMP;
      const int ics = lane & 31, ich = lane >> 5;
#pragma unroll
      for (int p = 0; p < 16; ++p) {
        int row = 1 + (p >> 2);
        int pos = row * 6 + 1 + (p & 3);
        int e = (row ^ (pos >> 2)) & 1;
        dst[pos * ROWE + ((ich ^ e) << 5) + ics] = (_Float16)fast_tanh(acc[p] + cinb);
      }
    }
    __syncthreads();

    // ---- c1: bufA -> bufB ----
    mid_layer_mfma(hp, hp + GS * SAMP, a1f, cb1, gbase, 0, wv, q, py, px);
    __syncthreads();

    // ---- c2: bufB -> bufA ----
    mid_layer_mfma(hp + GS * SAMP, hp, a2f, cb2, gbase, 64, wv, q, py, px);
    __syncthreads();

    // ---- cout: wave wv -> sample sg+wv; lane = (ic-quarter q, pixel m) ----
    {
      const _Float16* src = hp + wv * SAMP;
      const int c32 = q >> 1;
      const int coff = (q * 16) & 31;
      float acc = 0.0f;
#pragma unroll
      for (int tap = 0; tap < 9; ++tap) {
        const int ky = tap / 3, kx = tap % 3;
        const int row = py + ky;
        const int pos = row * 6 + px + kx;
        const int e = (row ^ (pos >> 2)) & 1;
        const _Float16* sp = src + pos * ROWE + ((c32 ^ e) << 5) + coff;
        half8 hv0 = *(const half8*)(sp);
        half8 hv1 = *(const half8*)(sp + 8);
        half8 wv0 = *(const half8*)(cwl + tap * 64 + q * 16);
        half8 wv1 = *(const half8*)(cwl + tap * 64 + q * 16 + 8);
#pragma unroll
        for (int j = 0; j < 4; ++j) {
          half2_t h2a = {hv0[2 * j], hv0[2 * j + 1]};
          half2_t w2a = {wv0[2 * j], wv0[2 * j + 1]};
          half2_t h2b = {hv1[2 * j], hv1[2 * j + 1]};
          half2_t w2b = {wv1[2 * j], wv1[2 * j + 1]};
#if __has_builtin(__builtin_amdgcn_fdot2)
          acc = __builtin_amdgcn_fdot2(h2a, w2a, acc, false);
          acc = __builtin_amdgcn_fdot2(h2b, w2b, acc, false);
#else
          acc += (float)h2a[0] * (float)w2a[0] + (float)h2a[1] * (float)w2a[1];
          acc += (float)h2b[0] * (float)w2b[0] + (float)h2b[1] * (float)w2b[1];
#endif
        }
      }
      acc += __shfl_xor(acc, 16);
      acc += __shfl_xor(acc, 32);
      if (q == 0) out[(size_t)(sg + wv) * 16 + m] = acc + cob;
    }
    __syncthreads();
  }
}

// ---------------------------------------------------------------------------
extern "C" void kernel_launch(void* const* d_in, const int* in_sizes, int n_in,
                              void* d_out, int out_size, void* d_ws, size_t ws_size,
                              hipStream_t stream) {
  const float* tt     = (const float*)d_in[0];
  const float* z      = (const float*)d_in[1];
  const float* mu     = (const float*)d_in[2];
  const float* W1     = (const float*)d_in[3];
  const float* b1     = (const float*)d_in[4];
  const float* W2     = (const float*)d_in[5];
  const float* b2     = (const float*)d_in[6];
  const float* Wg     = (const float*)d_in[7];
  const float* bg     = (const float*)d_in[8];
  const float* cin_w  = (const float*)d_in[9];
  const float* cin_b  = (const float*)d_in[10];
  const float* c1_w   = (const float*)d_in[11];
  const float* c1_b   = (const float*)d_in[12];
  const float* c2_w   = (const float*)d_in[13];
  const float* c2_b   = (const float*)d_in[14];
  const float* cout_w = (const float*)d_in[15];
  const float* cout_b = (const float*)d_in[16];

  float* out = (float*)d_out;
  _Float16* wt = (_Float16*)d_ws;   // 126976 f16 = 254 KB packed weights

  prep_kernel<<<496, 256, 0, stream>>>(W1, W2, Wg, c1_w, c2_w, wt);
  fused_kernel<<<NB / (GRPS * GS), 256, 0, stream>>>(
      tt, mu, z, wt, b1, b2, bg, cin_w, cin_b, c1_b, c2_b, cout_w, cout_b, out);
}